// Round 15
// baseline (49.138 us; speedup 1.0000x reference)
//
#include <hip/hip_runtime.h>
#include <hip/hip_bf16.h>
#include <math.h>

#define H 256
#define BQ 1024
#define NPOOL 32768
#define MAXN 64

typedef __attribute__((ext_vector_type(8))) short short8;
typedef __attribute__((ext_vector_type(8))) unsigned short ushort8v;
typedef __attribute__((ext_vector_type(4))) float f32x4;

__device__ __forceinline__ unsigned short f2bf(float f) {
  unsigned int u = __float_as_uint(f);
  unsigned int r = (u + 0x7fffu + ((u >> 16) & 1u)) >> 16;
  return (unsigned short)r;
}
__device__ __forceinline__ float b2f(unsigned short u) {
  return __uint_as_float((unsigned int)u << 16);
}
__device__ __forceinline__ unsigned int cvt_pk_bf16(float a, float b) {
  unsigned int r;
  asm("v_cvt_pk_bf16_f32 %0, %1, %2" : "=v"(r) : "v"(a), "v"(b));
  return r;
}
__device__ __forceinline__ void gload16(const void* g, void* l) {
  __builtin_amdgcn_global_load_lds(
      (const __attribute__((address_space(1))) unsigned int*)g,
      (__attribute__((address_space(3))) unsigned int*)l, 16, 0, 0);
}

// ---------------------------------------------------------------------------
// prep: transpose Wq(+scale)/Wk/Wv -> bf16 W^T (48 blocks); b<4 blocks also
// write bqs = bq * 0.0625 (scale folded: q = relu(enc@(Wq/16)+bq/16)).
// ---------------------------------------------------------------------------
__global__ __launch_bounds__(256) void prep_kernel(
    const float* __restrict__ Wq, const float* __restrict__ Wk,
    const float* __restrict__ Wv, const float* __restrict__ bq,
    unsigned short* __restrict__ WqT, unsigned short* __restrict__ WkT,
    unsigned short* __restrict__ WvT, float* __restrict__ bqs) {
  __shared__ float ls[64][65];
  const int b = blockIdx.x;
  const int t = threadIdx.x;
  const float* W = (b < 16) ? Wq : ((b < 32) ? Wk : Wv);
  unsigned short* WT = (b < 16) ? WqT : ((b < 32) ? WkT : WvT);
  const float scale = (b < 16) ? 0.0625f : 1.0f;
  const int tile = b & 15;
  const int k0 = (tile >> 2) * 64, c0 = (tile & 3) * 64;
  const int tx = t & 63, ty = t >> 6;
#pragma unroll
  for (int kk = 0; kk < 16; ++kk)
    ls[tx][kk * 4 + ty] = W[(size_t)(k0 + kk * 4 + ty) * H + c0 + tx];
  __syncthreads();
#pragma unroll
  for (int cc = 0; cc < 16; ++cc) {
    const int c = cc * 4 + ty;
    WT[(size_t)(c0 + c) * H + k0 + tx] = f2bf(ls[c][tx] * scale);
  }
  if (b < 4 && t < 64) bqs[c0 + t] = bq[c0 + t] * 0.0625f;
}

// ---------------------------------------------------------------------------
// gemm: unified QKV projection, A-read-once tiling.
// Block = 64 rows x 256 cols (ALL cols) of K AND V. BK=64, double-buffered:
// LDS = A[2][8K] + Bk[2][32K] + Bv[2][32K] = 144 KB. 512 threads (8 waves,
// 2/SIMD). A: fp32 -> regs -> cvt_pk -> swizzled ds_write; B: global_load_lds
// (pre-swizzled source, from L2-resident W^T). Counted vmcnt, raw barriers.
// bid<512: soc panel bid. bid>=512: enc panel (Q; Bk=Bv=WqT -> qbf twice).
// ---------------------------------------------------------------------------
__global__ __launch_bounds__(512) void gemm_kernel(
    const float* __restrict__ soc, const float* __restrict__ enc,
    const unsigned short* __restrict__ WkT,
    const unsigned short* __restrict__ WvT,
    const unsigned short* __restrict__ WqT,
    const float* __restrict__ bk, const float* __restrict__ bv,
    const float* __restrict__ bqs,
    unsigned short* __restrict__ kout, unsigned short* __restrict__ vout,
    unsigned short* __restrict__ qout) {
  // A[2][8192] @0 | Bk[2][32768] @16384 | Bv[2][32768] @81920 = 144 KB
  __shared__ __align__(16) char LDSb[147456];
  const int t = threadIdx.x;
  const int lane = t & 63, wid = t >> 6;
  const int bid = blockIdx.x;
  const bool isQ = bid >= 512;
  const int brow = (isQ ? (bid - 512) : bid) * 64;
  const float* Asrc = isQ ? enc : soc;
  const unsigned short* Bkg = isQ ? WqT : WkT;
  const unsigned short* Bvg = isQ ? WqT : WvT;
  const float* biask = isQ ? bqs : bk;
  const float* biasv = isQ ? bqs : bv;
  unsigned short* outk = isQ ? qout : kout;
  unsigned short* outv = isQ ? qout : vout;

  const int arow = t >> 3;   // 0..63  (A staging row; also B base row t>>3)
  const int aslot = t & 7;   // 16B slot

  f32x4 accK[4][2], accV[4][2];  // [n][m] : n=col-frag(4), m=row-frag(2)
#pragma unroll
  for (int n = 0; n < 4; ++n)
#pragma unroll
    for (int m = 0; m < 2; ++m) { accK[n][m] = (f32x4)0.f; accV[n][m] = (f32x4)0.f; }

  const int wr = wid >> 2, wc = wid & 3;  // wave: 32 rows x 64 cols

  float4 av[2];
  const float* asrc = Asrc + (size_t)(brow + arow) * H + aslot * 8;

  // A(kt): 8 consecutive fp32 -> regs (one 16B bf16 slot after cvt)
#define AREG_LOAD(kt)                                                 \
  {                                                                   \
    const float* p_ = asrc + (kt)*64;                                 \
    av[0] = *(const float4*)(p_);                                     \
    av[1] = *(const float4*)(p_ + 4);                                 \
  }
  // B(kt) -> half pb: 4 rows-chunks x 2 matrices, pre-swizzled source
#define STAGE_B(kt, pb)                                               \
  {                                                                   \
    const int k0_ = (kt)*64;                                          \
    char* bk_ = LDSb + 16384 + (pb)*32768;                            \
    char* bv_ = LDSb + 81920 + (pb)*32768;                            \
    _Pragma("unroll") for (int c = 0; c < 4; ++c) {                   \
      const int row_ = c * 64 + arow;                                 \
      const int ssrc_ = aslot ^ (row_ & 7);                           \
      gload16(Bkg + (size_t)row_ * H + k0_ + ssrc_ * 8,               \
              bk_ + c * 8192 + t * 16);                               \
      gload16(Bvg + (size_t)row_ * H + k0_ + ssrc_ * 8,               \
              bv_ + c * 8192 + t * 16);                               \
    }                                                                 \
  }
  // cvt av -> one 16B slot, swizzled ds_write into half pb
#define AWRITE(pb)                                                    \
  {                                                                   \
    uint4 p;                                                          \
    p.x = cvt_pk_bf16(av[0].x, av[0].y);                              \
    p.y = cvt_pk_bf16(av[0].z, av[0].w);                              \
    p.z = cvt_pk_bf16(av[1].x, av[1].y);                              \
    p.w = cvt_pk_bf16(av[1].z, av[1].w);                              \
    *(uint4*)(LDSb + (pb)*8192 + arow * 128 +                         \
              (aslot ^ (arow & 7)) * 16) = p;                         \
  }

  // prologue: tile 0
  AREG_LOAD(0);                                      // vm: A0(2)
  STAGE_B(0, 0);                                     // vm: A0(2) B0(8)
  asm volatile("s_waitcnt vmcnt(8)" ::: "memory");   // A0 regs arrived
  AWRITE(0);

#pragma unroll
  for (int kt = 0; kt < 4; ++kt) {
    const int cur = kt & 1;
    if (kt < 3) {
      AREG_LOAD(kt + 1);                             // +2
      STAGE_B(kt + 1, cur ^ 1);                      // +8 -> B(kt)=oldest 8
      asm volatile("s_waitcnt vmcnt(10)" ::: "memory");  // B(kt) landed
    } else {
      asm volatile("s_waitcnt vmcnt(0)" ::: "memory");
    }
    asm volatile("s_waitcnt lgkmcnt(0)" ::: "memory");  // my A-writes drained
    __builtin_amdgcn_s_barrier();                       // half `cur` staged
    const char* Ab = LDSb + cur * 8192;
    const char* Bkb = LDSb + 16384 + cur * 32768;
    const char* Bvb = LDSb + 81920 + cur * 32768;
#pragma unroll
    for (int kk = 0; kk < 2; ++kk) {
      short8 af[2], bkf[4], bvf[4];
#pragma unroll
      for (int m = 0; m < 2; ++m) {
        const int ar = wr * 32 + m * 16 + (lane & 15);
        const int sl = (kk * 4 + (lane >> 4)) ^ (ar & 7);
        af[m] = *(const short8*)(Ab + ar * 128 + sl * 16);
      }
#pragma unroll
      for (int n = 0; n < 4; ++n) {
        const int br = wc * 64 + n * 16 + (lane & 15);
        const int sl = (kk * 4 + (lane >> 4)) ^ (br & 7);
        bkf[n] = *(const short8*)(Bkb + br * 128 + sl * 16);
        bvf[n] = *(const short8*)(Bvb + br * 128 + sl * 16);
      }
#pragma unroll
      for (int n = 0; n < 4; ++n)
#pragma unroll
        for (int m = 0; m < 2; ++m) {
          accK[n][m] = __builtin_amdgcn_mfma_f32_16x16x32_bf16(
              af[m], bkf[n], accK[n][m], 0, 0, 0);
          accV[n][m] = __builtin_amdgcn_mfma_f32_16x16x32_bf16(
              af[m], bvf[n], accV[n][m], 0, 0, 0);
        }
    }
    if (kt < 3) {
      asm volatile("s_waitcnt vmcnt(8)" ::: "memory");  // A(kt+1) regs arrived
      AWRITE(cur ^ 1);
    }
    __builtin_amdgcn_s_barrier();  // all done reading half `cur`
  }
#undef AREG_LOAD
#undef STAGE_B
#undef AWRITE

  float bkn[4], bvn[4];
#pragma unroll
  for (int n = 0; n < 4; ++n) {
    const int col = wc * 64 + n * 16 + (lane & 15);
    bkn[n] = biask[col]; bvn[n] = biasv[col];
  }
#pragma unroll
  for (int n = 0; n < 4; ++n)
#pragma unroll
    for (int m = 0; m < 2; ++m) {
      const int col = wc * 64 + n * 16 + (lane & 15);
#pragma unroll
      for (int r = 0; r < 4; ++r) {
        const int row = brow + wr * 32 + m * 16 + (lane >> 4) * 4 + r;
        outk[(size_t)row * H + col] = f2bf(fmaxf(accK[n][m][r] + bkn[n], 0.f));
        outv[(size_t)row * H + col] = f2bf(fmaxf(accV[n][m][r] + bvn[n], 0.f));
      }
    }
}

// ---------------------------------------------------------------------------
// attn: per-sample sliced attention; q, k, v all bf16 (unchanged from r14)
// ---------------------------------------------------------------------------
__global__ __launch_bounds__(256) void attn_kernel(
    const unsigned short* __restrict__ qb,
    const unsigned short* __restrict__ kb,
    const unsigned short* __restrict__ vb, const int* __restrict__ starts,
    const int* __restrict__ ends, float* __restrict__ out) {
  __shared__ float sc[MAXN];
  const int row = blockIdx.x, t = threadIdx.x;
  const int lane = t & 63, wave = t >> 6;
  const int start = starts[row];
  const int len = ends[row] - start;  // 1..64

  const int qp = (lane & 31) * 8;
  const ushort8v q8 = *(const ushort8v*)(qb + (size_t)row * H + qp);
  float qf[8];
#pragma unroll
  for (int e = 0; e < 8; ++e) qf[e] = b2f(q8[e]);

  for (int jj = wave * 2; jj < len; jj += 8) {
    const int j0 = jj + (lane >> 5);
    if (j0 < len) {
      const ushort8v k8 =
          *(const ushort8v*)(kb + (size_t)(start + j0) * H + qp);
      float s = qf[0] * b2f(k8[0]) + qf[1] * b2f(k8[1]) +
                qf[2] * b2f(k8[2]) + qf[3] * b2f(k8[3]) +
                qf[4] * b2f(k8[4]) + qf[5] * b2f(k8[5]) +
                qf[6] * b2f(k8[6]) + qf[7] * b2f(k8[7]);
#pragma unroll
      for (int off = 16; off; off >>= 1) s += __shfl_xor(s, off, 64);
      if ((lane & 31) == 0) sc[j0] = s;
    }
  }
  __syncthreads();

  if (t < 64) {
    const float x = (t < len) ? sc[t] : -INFINITY;
    float m = x;
#pragma unroll
    for (int off = 32; off; off >>= 1) m = fmaxf(m, __shfl_xor(m, off, 64));
    const float p = (t < len) ? __expf(x - m) : 0.f;
    float ssum = p;
#pragma unroll
    for (int off = 32; off; off >>= 1) ssum += __shfl_xor(ssum, off, 64);
    sc[t] = p / ssum;
  }
  __syncthreads();

  const unsigned short* vp = vb + (size_t)start * H + t;
  float a0 = 0.f, a1 = 0.f, a2 = 0.f, a3 = 0.f;
  int j = 0;
  for (; j + 3 < len; j += 4) {
    a0 = fmaf(sc[j + 0], b2f(vp[(size_t)(j + 0) * H]), a0);
    a1 = fmaf(sc[j + 1], b2f(vp[(size_t)(j + 1) * H]), a1);
    a2 = fmaf(sc[j + 2], b2f(vp[(size_t)(j + 2) * H]), a2);
    a3 = fmaf(sc[j + 3], b2f(vp[(size_t)(j + 3) * H]), a3);
  }
  for (; j < len; ++j) a0 = fmaf(sc[j], b2f(vp[(size_t)j * H]), a0);
  out[(size_t)row * H + t] = (a0 + a1) + (a2 + a3);
}

// ---------------------------------------------------------------------------
extern "C" void kernel_launch(void* const* d_in, const int* in_sizes, int n_in,
                              void* d_out, int out_size, void* d_ws,
                              size_t ws_size, hipStream_t stream) {
  (void)in_sizes; (void)n_in; (void)out_size; (void)ws_size;
  const float* enc = (const float*)d_in[0];
  const float* soc = (const float*)d_in[1];
  const int* starts = (const int*)d_in[2];
  const int* ends = (const int*)d_in[3];
  const float* Wq = (const float*)d_in[4];
  const float* bq = (const float*)d_in[5];
  const float* Wk = (const float*)d_in[6];
  const float* bk = (const float*)d_in[7];
  const float* Wv = (const float*)d_in[8];
  const float* bv = (const float*)d_in[9];
  float* out = (float*)d_out;

  unsigned short* kb = (unsigned short*)d_ws;            // 16 MB
  unsigned short* vb = kb + (size_t)NPOOL * H;           // 16 MB
  unsigned short* WkT = vb + (size_t)NPOOL * H;          // 128 KB
  unsigned short* WvT = WkT + H * H;                     // 128 KB
  unsigned short* WqT = WvT + H * H;                     // 128 KB
  unsigned short* qbf = WqT + H * H;                     // 512 KB (BQ*H bf16)
  float* bqs = (float*)(qbf + (size_t)BQ * H);           // 1 KB

  prep_kernel<<<48, 256, 0, stream>>>(Wq, Wk, Wv, bq, WqT, WkT, WvT, bqs);
  gemm_kernel<<<528, 512, 0, stream>>>(soc, enc, WkT, WvT, WqT, bk, bv, bqs,
                                       kb, vb, qbf);
  attn_kernel<<<BQ, 256, 0, stream>>>(qbf, kb, vb, starts, ends, out);
}